// Round 11
// baseline (511.898 us; speedup 1.0000x reference)
//
#include <hip/hip_runtime.h>

// GNN: 3x (GCNConv -> BN(eval) -> ReLU) -> global_mean_pool -> MLP head.
// N=100000 nodes, E=3.2M edges, G=64 graphs, C_IN=32, H=128.
// R10 changes vs R9 (agg128 75us, VALUBusy 85% = VALU-issue-bound; 16 gathers
// + 4 id loads per 32 edges):
//  - agg128: 4 edge-groups x 16 lanes, dwordx2 row slices -> 8 gathers + 2
//    int4 id loads per 32 edges (halved). Same decode VALU; deep ILP kept.
//  - agg32: 16 edge-groups x 4 lanes, dwordx2 -> 2 gathers + 1 int2 id load
//    per 32 edges.
//  - BN (sc, bs) pre-folded by bn_prep kernel; agg epilogues load 4x float4.
// Carried: padded CSR (lists multiple of 4, dummy node n with zero row),
// scale-free fp8 messages (QS=16), radix-partition CSR build, MFMA bf16
// GEMMs with fused epilogues, bf16 h buffers, 2-stage pool.

#define EPSL 1e-5f
#define HD 128
#define PB 256
#define MAXB 512
#define QS 16.f
#define RQS (1.f / 16.f)

typedef __attribute__((ext_vector_type(8))) short bf16x8;
typedef __attribute__((ext_vector_type(8))) unsigned short u16x8;
typedef __attribute__((ext_vector_type(4))) float f32x4;
typedef __attribute__((ext_vector_type(2))) float f32x2;

__device__ __forceinline__ int lower_bound_i(const int* a, int n, int key) {
  int lo = 0, hi = n;
  while (lo < hi) { int mid = (lo + hi) >> 1; if (a[mid] < key) lo = mid + 1; else hi = mid; }
  return lo;
}

__device__ __forceinline__ ushort f2bf(float f) {
  union { float f; uint u; } v; v.f = f;
  uint u = v.u;
  return (ushort)((u + 0x7fffu + ((u >> 16) & 1u)) >> 16);
}
__device__ __forceinline__ float bf2f(ushort u) { return __int_as_float(((uint)u) << 16); }

// fp8 e4m3 dword decode-accumulate: 2 cvt_pk + 2 packed f32 adds, 4 channels
__device__ __forceinline__ void accf8v(f32x2* a, uint w) {
  a[0] += __builtin_amdgcn_cvt_pk_f32_fp8(w, false);
  a[1] += __builtin_amdgcn_cvt_pk_f32_fp8(w, true);
}

// ---- CSR build: radix partition by dst>>8 ---------------------------------

__global__ __launch_bounds__(256) void hist_kernel(const int* __restrict__ dst,
                                                   int* __restrict__ histT, int e_total,
                                                   int epb, int nbkt) {
  __shared__ int cnt[MAXB];
  int tid = threadIdx.x;
  for (int b = tid; b < nbkt; b += 256) cnt[b] = 0;
  __syncthreads();
  int e0 = blockIdx.x * epb;
  int e1 = min(e0 + epb, e_total);
  for (int e = e0 + tid; e < e1; e += 256) atomicAdd(&cnt[dst[e] >> 8], 1);
  __syncthreads();
  for (int b = tid; b < nbkt; b += 256) histT[b * PB + blockIdx.x] = cnt[b];
}

__global__ __launch_bounds__(256) void scanA_kernel(const int* __restrict__ cnt,
                                                    int* __restrict__ bsum, int n) {
  __shared__ int sd[256];
  int tid = threadIdx.x;
  int i0 = blockIdx.x * 4096 + tid * 16;
  int lsum = 0;
#pragma unroll
  for (int j = 0; j < 16; ++j) { int idx = i0 + j; lsum += (idx < n) ? cnt[idx] : 0; }
  sd[tid] = lsum;
  __syncthreads();
  for (int off = 128; off > 0; off >>= 1) {
    if (tid < off) sd[tid] += sd[tid + off];
    __syncthreads();
  }
  if (tid == 0) bsum[blockIdx.x] = sd[0];
}

__global__ void scanB_kernel(const int* __restrict__ bsum, int* __restrict__ boffs, int nb) {
  if (threadIdx.x == 0 && blockIdx.x == 0) {
    int run = 0;
    for (int k = 0; k < nb; ++k) { boffs[k] = run; run += bsum[k]; }
  }
}

__global__ __launch_bounds__(256) void scanC_kernel(const int* __restrict__ cnt,
                                                    const int* __restrict__ boffs,
                                                    int* __restrict__ offs, int n) {
  __shared__ int sd[256];
  int tid = threadIdx.x;
  int i0 = blockIdx.x * 4096 + tid * 16;
  int loc[16];
  int lsum = 0;
#pragma unroll
  for (int j = 0; j < 16; ++j) {
    int idx = i0 + j;
    int v = (idx < n) ? cnt[idx] : 0;
    loc[j] = lsum;
    lsum += v;
  }
  sd[tid] = lsum;
  __syncthreads();
  int x = lsum;
  for (int off = 1; off < 256; off <<= 1) {
    int t = (tid >= off) ? sd[tid - off] : 0;
    __syncthreads();
    x += t;
    sd[tid] = x;
    __syncthreads();
  }
  int texcl = boffs[blockIdx.x] + x - lsum;
#pragma unroll
  for (int j = 0; j < 16; ++j) {
    int idx = i0 + j;
    if (idx < n) offs[idx] = texcl + loc[j];
  }
}

__global__ __launch_bounds__(256) void bucket_scatter_kernel(const int* __restrict__ src,
                                                             const int* __restrict__ dst,
                                                             const int* __restrict__ offsT,
                                                             uint* __restrict__ packed,
                                                             int e_total, int epb, int nbkt) {
  __shared__ int cur[MAXB];
  int tid = threadIdx.x;
  for (int b = tid; b < nbkt; b += 256) cur[b] = offsT[b * PB + blockIdx.x];
  __syncthreads();
  int e0 = blockIdx.x * epb;
  int e1 = min(e0 + epb, e_total);
  for (int e = e0 + tid; e < e1; e += 256) {
    int s = src[e], d = dst[e];
    int pos = atomicAdd(&cur[d >> 8], 1);
    packed[pos] = ((uint)(d & 255) << 24) | (uint)s;
  }
}

// per-bucket local CSR (padded to multiple of 4, pads -> dummy node n),
// + dinv + fp8 encode of x rows. Bucket base claimed via global atomic.
__global__ __launch_bounds__(256) void bucket_csr_kernel(const uint* __restrict__ packed,
                                                         const int* __restrict__ offsT,
                                                         const float* __restrict__ x,
                                                         int* __restrict__ row_start,
                                                         int* __restrict__ pcnt,
                                                         float* __restrict__ dinv,
                                                         int* __restrict__ edge_src,
                                                         uint* __restrict__ xs8,
                                                         int* __restrict__ cursor,
                                                         int n, int e_total, int nbkt) {
  __shared__ int cnt[256];
  __shared__ int sd[256];
  __shared__ int cur[256];
  __shared__ int s_base;
  int tid = threadIdx.x;
  int bkt = blockIdx.x;
  int base = bkt << 8;
  int nn = min(256, n - base);
  int e0 = offsT[bkt * PB];
  int e1 = (bkt + 1 < nbkt) ? offsT[(bkt + 1) * PB] : e_total;
  cnt[tid] = 0;
  __syncthreads();
  for (int e = e0 + tid; e < e1; e += 256) atomicAdd(&cnt[packed[e] >> 24], 1);
  __syncthreads();
  int myc = cnt[tid];
  int myc4 = (myc + 3) & ~3;  // pad to multiple of 4 (int4-aligned lists)
  sd[tid] = myc4;
  __syncthreads();
  int x_ = myc4;
  for (int off = 1; off < 256; off <<= 1) {
    int t = (tid >= off) ? sd[tid - off] : 0;
    __syncthreads();
    x_ += t;
    sd[tid] = x_;
    __syncthreads();
  }
  int excl4 = x_ - myc4;
  if (tid == 255) s_base = atomicAdd(cursor, x_);  // x_ at tid 255 = bucket total
  __syncthreads();
  int start = s_base + excl4;
  float dsc = rsqrtf((float)(myc + 1));  // +1 self loop
  if (tid < nn) {
    int node = base + tid;
    row_start[node] = start;
    pcnt[node] = myc4;
    dinv[node] = dsc;
    float rcp = dsc * QS;
    uint rowq[8];
#pragma unroll
    for (int j = 0; j < 8; ++j) {
      float4 v = *(const float4*)&x[(size_t)node * 32 + j * 4];
      int p = 0;
      p = __builtin_amdgcn_cvt_pk_fp8_f32(v.x * rcp, v.y * rcp, p, false);
      p = __builtin_amdgcn_cvt_pk_fp8_f32(v.z * rcp, v.w * rcp, p, true);
      rowq[j] = (uint)p;
    }
    *(uint4*)&xs8[(size_t)node * 8] = *(uint4*)&rowq[0];
    *(uint4*)&xs8[(size_t)node * 8 + 4] = *(uint4*)&rowq[4];
    for (int p = myc; p < myc4; ++p) edge_src[start + p] = n;  // pad -> dummy
  }
  cur[tid] = start;
  __syncthreads();
  for (int e = e0 + tid; e < e1; e += 256) {
    uint p = packed[e];
    int pos = atomicAdd(&cur[p >> 24], 1);
    edge_src[pos] = (int)(p & 0xFFFFFFu);
  }
}

// ---- BN constant pre-fold (layers 2 and 3) --------------------------------

__global__ void bn_prep_kernel(const float* __restrict__ b2, const float* __restrict__ g2,
                               const float* __restrict__ beta2, const float* __restrict__ rm2,
                               const float* __restrict__ rv2, const float* __restrict__ b3,
                               const float* __restrict__ g3, const float* __restrict__ beta3,
                               const float* __restrict__ rm3, const float* __restrict__ rv3,
                               float* __restrict__ scv, float* __restrict__ bsv) {
  int c = threadIdx.x;
  const float *b, *g, *bt, *rm, *rv;
  float *scp, *bsp;
  if (blockIdx.x == 0) { b = b2; g = g2; bt = beta2; rm = rm2; rv = rv2; scp = scv; bsp = bsv; }
  else { b = b3; g = g3; bt = beta3; rm = rm3; rv = rv3; scp = scv + 128; bsp = bsv + 128; }
  float s = g[c] * rsqrtf(rv[c] + EPSL);
  scp[c] = s;
  bsp[c] = (b[c] - rm[c]) * s + bt[c];
}

// ---- Aggregation ----------------------------------------------------------

// 32-dim fp8 agg: 16 edge-groups x 4 lanes (dwordx2 slice); 32 edges/iter =
// 2 gathers + 1 int2 id load; masked tail; pads hit dummy zero row.
__global__ __launch_bounds__(256) void agg32_kernel(const uint2* __restrict__ xs2,
                                                    const float* __restrict__ dinv,
                                                    const int* __restrict__ row_start,
                                                    const int* __restrict__ pcnt,
                                                    const int* __restrict__ edge_src,
                                                    ushort* __restrict__ out16, int n) {
  int wave = (blockIdx.x * blockDim.x + threadIdx.x) >> 6;
  if (wave >= n) return;
  int lane = threadIdx.x & 63;
  int eg = lane >> 2, dpos = lane & 3;
  int i = wave;
  int r0 = __builtin_amdgcn_readfirstlane(row_start[i]);
  int pc = __builtin_amdgcn_readfirstlane(pcnt[i]);
  int r1 = r0 + pc;
  f32x2 A[4] = {}, B[4] = {};
  if (eg == 0) {
    uint2 w = xs2[(size_t)i * 4 + dpos];
    accf8v(A, w.x);
    accf8v(A + 2, w.y);
  }
  int nfull = pc & ~31;
  int e = r0;
  for (; e < r0 + nfull; e += 32) {
    const int* ep = edge_src + e + 2 * eg;
    int2 ii = *(const int2*)ep;
    uint2 w0 = xs2[(size_t)ii.x * 4 + dpos];
    uint2 w1 = xs2[(size_t)ii.y * 4 + dpos];
    accf8v(A, w0.x);
    accf8v(A + 2, w0.y);
    accf8v(B, w1.x);
    accf8v(B + 2, w1.y);
  }
  if (e < r1) {
    int base2 = e + 2 * eg;
    const int* ep = edge_src + base2;
    int2 ii = *(const int2*)ep;
    uint2 w0 = xs2[(size_t)ii.x * 4 + dpos];
    uint2 w1 = xs2[(size_t)ii.y * 4 + dpos];
    uint m0 = (base2 + 0 < r1) ? 0xFFFFFFFFu : 0u;
    uint m1 = (base2 + 1 < r1) ? 0xFFFFFFFFu : 0u;
    accf8v(A, w0.x & m0);
    accf8v(A + 2, w0.y & m0);
    accf8v(B, w1.x & m1);
    accf8v(B + 2, w1.y & m1);
  }
  A[0] += B[0]; A[1] += B[1]; A[2] += B[2]; A[3] += B[3];
  float aa[8] = {A[0].x, A[0].y, A[1].x, A[1].y, A[2].x, A[2].y, A[3].x, A[3].y};
#pragma unroll
  for (int j = 0; j < 8; ++j) {
    aa[j] += __shfl_xor(aa[j], 4, 64);
    aa[j] += __shfl_xor(aa[j], 8, 64);
    aa[j] += __shfl_xor(aa[j], 16, 64);
    aa[j] += __shfl_xor(aa[j], 32, 64);
  }
  if (eg == 0) {
    float dq = dinv[i] * RQS;
    int c0 = dpos * 8;
    u16x8 o;
#pragma unroll
    for (int j = 0; j < 8; ++j) o[j] = f2bf(dq * aa[j]);
    *(u16x8*)&out16[(size_t)i * 32 + c0] = o;
  }
}

// 128-dim fp8 agg: 4 edge-groups x 16 lanes (dwordx2 slice); 32 edges/iter =
// 8 gathers + 2 int4 id loads; one masked tail; fused BN+ReLU -> bf16.
__global__ __launch_bounds__(256) void agg128_f8_kernel(const uint2* __restrict__ f8,
                                                        const float* __restrict__ dinv,
                                                        const int* __restrict__ row_start,
                                                        const int* __restrict__ pcnt,
                                                        const int* __restrict__ edge_src,
                                                        const float* __restrict__ scv,
                                                        const float* __restrict__ bsv,
                                                        ushort* __restrict__ out16, int n) {
  int wave = (blockIdx.x * blockDim.x + threadIdx.x) >> 6;
  if (wave >= n) return;
  int lane = threadIdx.x & 63;
  int eg = lane >> 4, dpos = lane & 15;
  int i = wave;
  int r0 = __builtin_amdgcn_readfirstlane(row_start[i]);
  int pc = __builtin_amdgcn_readfirstlane(pcnt[i]);
  int r1 = r0 + pc;
  f32x2 A[4] = {}, B[4] = {};
  if (eg == 0) {
    uint2 w = f8[(size_t)i * 16 + dpos];
    accf8v(A, w.x);
    accf8v(A + 2, w.y);
  }
  int nfull = pc & ~31;
  int e = r0;
  for (; e < r0 + nfull; e += 32) {
    const int* ep = edge_src + e + 8 * eg;
    int4 ia = *(const int4*)ep;
    int4 ib = *(const int4*)(ep + 4);
    uint2 w0 = f8[(size_t)ia.x * 16 + dpos];
    uint2 w1 = f8[(size_t)ia.y * 16 + dpos];
    uint2 w2 = f8[(size_t)ia.z * 16 + dpos];
    uint2 w3 = f8[(size_t)ia.w * 16 + dpos];
    uint2 w4 = f8[(size_t)ib.x * 16 + dpos];
    uint2 w5 = f8[(size_t)ib.y * 16 + dpos];
    uint2 w6 = f8[(size_t)ib.z * 16 + dpos];
    uint2 w7 = f8[(size_t)ib.w * 16 + dpos];
    accf8v(A, w0.x); accf8v(A + 2, w0.y);
    accf8v(B, w1.x); accf8v(B + 2, w1.y);
    accf8v(A, w2.x); accf8v(A + 2, w2.y);
    accf8v(B, w3.x); accf8v(B + 2, w3.y);
    accf8v(A, w4.x); accf8v(A + 2, w4.y);
    accf8v(B, w5.x); accf8v(B + 2, w5.y);
    accf8v(A, w6.x); accf8v(A + 2, w6.y);
    accf8v(B, w7.x); accf8v(B + 2, w7.y);
  }
  if (e < r1) {
    int base2 = e + 8 * eg;
    const int* ep = edge_src + base2;
    int4 ia = *(const int4*)ep;
    int4 ib = *(const int4*)(ep + 4);
    uint2 w0 = f8[(size_t)ia.x * 16 + dpos];
    uint2 w1 = f8[(size_t)ia.y * 16 + dpos];
    uint2 w2 = f8[(size_t)ia.z * 16 + dpos];
    uint2 w3 = f8[(size_t)ia.w * 16 + dpos];
    uint2 w4 = f8[(size_t)ib.x * 16 + dpos];
    uint2 w5 = f8[(size_t)ib.y * 16 + dpos];
    uint2 w6 = f8[(size_t)ib.z * 16 + dpos];
    uint2 w7 = f8[(size_t)ib.w * 16 + dpos];
    uint m0 = (base2 + 0 < r1) ? 0xFFFFFFFFu : 0u;
    uint m1 = (base2 + 1 < r1) ? 0xFFFFFFFFu : 0u;
    uint m2 = (base2 + 2 < r1) ? 0xFFFFFFFFu : 0u;
    uint m3 = (base2 + 3 < r1) ? 0xFFFFFFFFu : 0u;
    uint m4 = (base2 + 4 < r1) ? 0xFFFFFFFFu : 0u;
    uint m5 = (base2 + 5 < r1) ? 0xFFFFFFFFu : 0u;
    uint m6 = (base2 + 6 < r1) ? 0xFFFFFFFFu : 0u;
    uint m7 = (base2 + 7 < r1) ? 0xFFFFFFFFu : 0u;
    accf8v(A, w0.x & m0); accf8v(A + 2, w0.y & m0);
    accf8v(B, w1.x & m1); accf8v(B + 2, w1.y & m1);
    accf8v(A, w2.x & m2); accf8v(A + 2, w2.y & m2);
    accf8v(B, w3.x & m3); accf8v(B + 2, w3.y & m3);
    accf8v(A, w4.x & m4); accf8v(A + 2, w4.y & m4);
    accf8v(B, w5.x & m5); accf8v(B + 2, w5.y & m5);
    accf8v(A, w6.x & m6); accf8v(A + 2, w6.y & m6);
    accf8v(B, w7.x & m7); accf8v(B + 2, w7.y & m7);
  }
  A[0] += B[0]; A[1] += B[1]; A[2] += B[2]; A[3] += B[3];
  float aa[8] = {A[0].x, A[0].y, A[1].x, A[1].y, A[2].x, A[2].y, A[3].x, A[3].y};
#pragma unroll
  for (int j = 0; j < 8; ++j) {
    aa[j] += __shfl_xor(aa[j], 16, 64);
    aa[j] += __shfl_xor(aa[j], 32, 64);
  }
  if (eg == 0) {
    float dq = dinv[i] * RQS;
    int c0 = dpos * 8;
    float4 s0 = *(const float4*)&scv[c0];
    float4 s1 = *(const float4*)&scv[c0 + 4];
    float4 h0 = *(const float4*)&bsv[c0];
    float4 h1 = *(const float4*)&bsv[c0 + 4];
    u16x8 o;
    o[0] = f2bf(fmaxf(aa[0] * dq * s0.x + h0.x, 0.f));
    o[1] = f2bf(fmaxf(aa[1] * dq * s0.y + h0.y, 0.f));
    o[2] = f2bf(fmaxf(aa[2] * dq * s0.z + h0.z, 0.f));
    o[3] = f2bf(fmaxf(aa[3] * dq * s0.w + h0.w, 0.f));
    o[4] = f2bf(fmaxf(aa[4] * dq * s1.x + h1.x, 0.f));
    o[5] = f2bf(fmaxf(aa[5] * dq * s1.y + h1.y, 0.f));
    o[6] = f2bf(fmaxf(aa[6] * dq * s1.z + h1.z, 0.f));
    o[7] = f2bf(fmaxf(aa[7] * dq * s1.w + h1.w, 0.f));
    *(u16x8*)&out16[(size_t)i * HD + c0] = o;
  }
}

// ---- MFMA GEMMs -----------------------------------------------------------
// mfma_f32_16x16x32_bf16: A lane l: A[l&15][(l>>4)*8+j]; B: B[(l>>4)*8+j][l&15];
// D lane l reg r: D[(l>>4)*4+r][l&15].

__global__ __launch_bounds__(256) void mfma_gemm_l1(const ushort* __restrict__ A,
                                                    const float* __restrict__ W,
                                                    const float* __restrict__ b,
                                                    const float* __restrict__ g,
                                                    const float* __restrict__ beta,
                                                    const float* __restrict__ rm,
                                                    const float* __restrict__ rv,
                                                    ushort* __restrict__ out, int ntiles) {
  __shared__ ushort sWT[128][40];
  int tid = threadIdx.x;
  for (int idx = tid; idx < 32 * 128; idx += 256) {
    int k = idx >> 7, c = idx & 127;
    sWT[c][k] = f2bf(W[idx]);
  }
  __syncthreads();
  int lane = tid & 63, wid = tid >> 6;
  int q = lane & 15, hk = lane >> 4;
  float sc[8], bs[8];
#pragma unroll
  for (int t = 0; t < 8; ++t) {
    int c = t * 16 + q;
    float s = g[c] * rsqrtf(rv[c] + EPSL);
    sc[t] = s;
    bs[t] = (b[c] - rm[c]) * s + beta[c];
  }
  for (int tile = blockIdx.x * 4 + wid; tile < ntiles; tile += gridDim.x * 4) {
    int row0 = tile * 16;
    bf16x8 a = *(const bf16x8*)&A[(size_t)(row0 + q) * 32 + hk * 8];
    f32x4 acc[8];
#pragma unroll
    for (int t = 0; t < 8; ++t) {
      f32x4 z = {0.f, 0.f, 0.f, 0.f};
      bf16x8 bf = *(const bf16x8*)&sWT[t * 16 + q][hk * 8];
      acc[t] = __builtin_amdgcn_mfma_f32_16x16x32_bf16(a, bf, z, 0, 0, 0);
    }
#pragma unroll
    for (int t = 0; t < 8; ++t)
#pragma unroll
      for (int r = 0; r < 4; ++r) {
        float v = fmaxf(acc[t][r] * sc[t] + bs[t], 0.f);
        out[(size_t)(row0 + hk * 4 + r) * HD + t * 16 + q] = f2bf(v);
      }
  }
}

__global__ __launch_bounds__(256) void mfma_gemm_f8(const ushort* __restrict__ A,
                                                    const float* __restrict__ W,
                                                    const float* __restrict__ dinv,
                                                    uint* __restrict__ f8out, int ntiles) {
  __shared__ ushort sWT[128][136];
  __shared__ ushort dtile[4][16][132];
  int tid = threadIdx.x;
  for (int idx = tid; idx < 128 * 128; idx += 256) {
    int k = idx >> 7, c = idx & 127;
    sWT[c][k] = f2bf(W[idx]);
  }
  __syncthreads();
  int lane = tid & 63, wid = tid >> 6;
  int q = lane & 15, hk = lane >> 4;
  int lr = lane >> 2, ch = lane & 3;
  for (int tile = blockIdx.x * 4 + wid; tile < ntiles; tile += gridDim.x * 4) {
    int row0 = tile * 16;
    f32x4 acc[8] = {};
#pragma unroll
    for (int kk = 0; kk < 128; kk += 32) {
      bf16x8 a = *(const bf16x8*)&A[(size_t)(row0 + q) * HD + kk + hk * 8];
#pragma unroll
      for (int t = 0; t < 8; ++t) {
        bf16x8 bf = *(const bf16x8*)&sWT[t * 16 + q][kk + hk * 8];
        acc[t] = __builtin_amdgcn_mfma_f32_16x16x32_bf16(a, bf, acc[t], 0, 0, 0);
      }
    }
    float dS[4];
#pragma unroll
    for (int r = 0; r < 4; ++r) dS[r] = dinv[row0 + hk * 4 + r] * QS;
#pragma unroll
    for (int t = 0; t < 8; ++t)
#pragma unroll
      for (int r = 0; r < 4; ++r)
        dtile[wid][hk * 4 + r][t * 16 + q] = f2bf(acc[t][r] * dS[r]);
    uint pq[8];
#pragma unroll
    for (int j = 0; j < 4; ++j) {
      bf16x8 v = *(bf16x8*)&dtile[wid][lr][ch * 32 + j * 8];
      int p0 = 0, p1 = 0;
      p0 = __builtin_amdgcn_cvt_pk_fp8_f32(bf2f((ushort)v[0]), bf2f((ushort)v[1]), p0, false);
      p0 = __builtin_amdgcn_cvt_pk_fp8_f32(bf2f((ushort)v[2]), bf2f((ushort)v[3]), p0, true);
      p1 = __builtin_amdgcn_cvt_pk_fp8_f32(bf2f((ushort)v[4]), bf2f((ushort)v[5]), p1, false);
      p1 = __builtin_amdgcn_cvt_pk_fp8_f32(bf2f((ushort)v[6]), bf2f((ushort)v[7]), p1, true);
      pq[j * 2] = (uint)p0;
      pq[j * 2 + 1] = (uint)p1;
    }
    int orow = row0 + lr;
    *(int4*)&f8out[(size_t)orow * 32 + ch * 8] = *(int4*)&pq[0];
    *(int4*)&f8out[(size_t)orow * 32 + ch * 8 + 4] = *(int4*)&pq[4];
  }
}

// ---- Pool (2-stage, bf16 packed) + MLP head --------------------------------

__global__ __launch_bounds__(256) void pool1_kernel(const uint* __restrict__ h2,
                                                    const int* __restrict__ batch,
                                                    float* __restrict__ gsums, int n) {
  const int CH = 512;
  int r0 = blockIdx.x * CH;
  int col2 = threadIdx.x & 63;
  int part = threadIdx.x >> 6;
  int rend = min(r0 + CH, n);
  float acc0 = 0.f, acc1 = 0.f;
  int gcur = -1;
  for (int r = r0 + part; r < rend; r += 4) {
    int gg = batch[r];
    uint w = h2[(size_t)r * 64 + col2];
    if (gg != gcur) {
      if (gcur >= 0) {
        atomicAdd(&gsums[gcur * HD + col2 * 2], acc0);
        atomicAdd(&gsums[gcur * HD + col2 * 2 + 1], acc1);
      }
      acc0 = 0.f;
      acc1 = 0.f;
      gcur = gg;
    }
    acc0 += bf2f((ushort)(w & 0xffffu));
    acc1 += bf2f((ushort)(w >> 16));
  }
  if (gcur >= 0) {
    atomicAdd(&gsums[gcur * HD + col2 * 2], acc0);
    atomicAdd(&gsums[gcur * HD + col2 * 2 + 1], acc1);
  }
}

__global__ __launch_bounds__(128) void head_kernel(const float* __restrict__ gsums,
                                                   const int* __restrict__ batch,
                                                   const float* __restrict__ We,
                                                   const float* __restrict__ be,
                                                   const float* __restrict__ Wc1,
                                                   const float* __restrict__ bc1,
                                                   const float* __restrict__ Wc2,
                                                   const float* __restrict__ bc2,
                                                   float* __restrict__ outp, int n) {
  int g = blockIdx.x;
  int tid = threadIdx.x;
  int lo = lower_bound_i(batch, n, g);
  int hi = lower_bound_i(batch, n, g + 1);
  __shared__ float xrow[128];
  __shared__ float erow[128];
  __shared__ float hrow[64];
  float cnt = (float)(hi - lo);
  xrow[tid] = gsums[g * HD + tid] / fmaxf(cnt, 1.f);
  __syncthreads();
  float acc = be[tid];
#pragma unroll 4
  for (int k = 0; k < 128; ++k) acc += xrow[k] * We[k * 128 + tid];
  erow[tid] = fmaxf(acc, 0.f);
  __syncthreads();
  if (tid < 64) {
    float a2 = bc1[tid];
#pragma unroll 4
    for (int k = 0; k < 128; ++k) a2 += erow[k] * Wc1[k * 64 + tid];
    hrow[tid] = fmaxf(a2, 0.f);
  }
  __syncthreads();
  if (tid < 64) {
    float v = hrow[tid] * Wc2[tid];
#pragma unroll
    for (int off = 32; off > 0; off >>= 1) v += __shfl_down(v, off, 64);
    if (tid == 0) outp[g] = v + bc2[0];
  }
}

// ---- launch ---------------------------------------------------------------

extern "C" void kernel_launch(void* const* d_in, const int* in_sizes, int n_in,
                              void* d_out, int out_size, void* d_ws, size_t ws_size,
                              hipStream_t stream) {
  const float* x = (const float*)d_in[0];
  const int* edge_index = (const int*)d_in[1];
  const int* batch = (const int*)d_in[2];
  const float* W1 = (const float*)d_in[3];
  const float* b1 = (const float*)d_in[4];
  const float* W2 = (const float*)d_in[5];
  const float* b2 = (const float*)d_in[6];
  const float* W3 = (const float*)d_in[7];
  const float* b3 = (const float*)d_in[8];
  const float* g1 = (const float*)d_in[9];
  const float* beta1 = (const float*)d_in[10];
  const float* rm1 = (const float*)d_in[11];
  const float* rv1 = (const float*)d_in[12];
  const float* g2 = (const float*)d_in[13];
  const float* beta2 = (const float*)d_in[14];
  const float* rm2 = (const float*)d_in[15];
  const float* rv2 = (const float*)d_in[16];
  const float* g3 = (const float*)d_in[17];
  const float* beta3 = (const float*)d_in[18];
  const float* rm3 = (const float*)d_in[19];
  const float* rv3 = (const float*)d_in[20];
  const float* We = (const float*)d_in[21];
  const float* be = (const float*)d_in[22];
  const float* Wc1 = (const float*)d_in[23];
  const float* bc1 = (const float*)d_in[24];
  const float* Wc2 = (const float*)d_in[25];
  const float* bc2 = (const float*)d_in[26];

  const int N = in_sizes[0] / 32;
  const int E = in_sizes[1] / 2;
  const int G = out_size;
  const int* esrc = edge_index;
  const int* edst = edge_index + E;

  const int NBKT = (N + 255) >> 8;
  const int EPB = (E + PB - 1) / PB;
  const int N2 = NBKT * PB;
  const int NB2 = (N2 + 4095) / 4096;
  const int NT = N / 16;  // N = 100000 divisible by 16
  const int EPAD = E + 4 * N + 64;

  char* ws = (char*)d_ws;
  size_t cur = 0;
  auto alloc = [&](size_t bytes) {
    size_t o = cur;
    cur += (bytes + 255) & ~(size_t)255;
    return o;
  };
  int* histT = (int*)(ws + alloc((size_t)N2 * 4));
  uint* packed = (uint*)(ws + alloc((size_t)E * 4));
  int* edge_src = (int*)(ws + alloc((size_t)EPAD * 4));
  int* row_start = (int*)(ws + alloc((size_t)N * 4));
  int* pcnt = (int*)(ws + alloc((size_t)N * 4));
  float* dinv = (float*)(ws + alloc((size_t)N * 4));
  int* bsum = (int*)(ws + alloc(256 * 4));
  int* boffs = (int*)(ws + alloc(256 * 4));
  int* cursor = (int*)(ws + alloc(256));
  float* scv = (float*)(ws + alloc(256 * 4));
  float* bsv = (float*)(ws + alloc(256 * 4));
  uint* xs8 = (uint*)(ws + alloc((size_t)(N + 1) * 8 * 4));       // fp8 x rows + dummy
  ushort* aggX = (ushort*)(ws + alloc((size_t)N * 32 * 2));       // bf16 [N][32]
  ushort* hbuf = (ushort*)(ws + alloc((size_t)N * HD * 2));       // bf16 [N][128]
  uint* f8buf = (uint*)(ws + alloc((size_t)(N + 1) * 32 * 4));    // fp8 rows + dummy
  float* gsums = (float*)(ws + alloc((size_t)G * HD * 4));

  hipMemsetAsync(gsums, 0, (size_t)G * HD * 4, stream);
  hipMemsetAsync(cursor, 0, 4, stream);
  hipMemsetAsync(edge_src + E, 0, (size_t)(4 * N + 64) * 4, stream);  // pad window
  hipMemsetAsync(xs8 + (size_t)N * 8, 0, 32, stream);                 // dummy row
  hipMemsetAsync(f8buf + (size_t)N * 32, 0, 128, stream);             // dummy row

  bn_prep_kernel<<<2, 128, 0, stream>>>(b2, g2, beta2, rm2, rv2, b3, g3, beta3, rm3, rv3, scv,
                                        bsv);

  // CSR build (no global atomics in hot passes) + dinv + fp8 x rows
  hist_kernel<<<PB, 256, 0, stream>>>(edst, histT, E, EPB, NBKT);
  scanA_kernel<<<NB2, 256, 0, stream>>>(histT, bsum, N2);
  scanB_kernel<<<1, 64, 0, stream>>>(bsum, boffs, NB2);
  scanC_kernel<<<NB2, 256, 0, stream>>>(histT, boffs, histT, N2);
  bucket_scatter_kernel<<<PB, 256, 0, stream>>>(esrc, edst, histT, packed, E, EPB, NBKT);
  bucket_csr_kernel<<<NBKT, 256, 0, stream>>>(packed, histT, x, row_start, pcnt, dinv, edge_src,
                                              xs8, cursor, N, E, NBKT);

  // Layer 1: fp8 agg32 (bf16 out) -> MFMA gemm (BN1+ReLU -> bf16 h1)
  agg32_kernel<<<(N + 3) / 4, 256, 0, stream>>>((const uint2*)xs8, dinv, row_start, pcnt,
                                                edge_src, aggX, N);
  mfma_gemm_l1<<<512, 256, 0, stream>>>(aggX, W1, b1, g1, beta1, rm1, rv1, hbuf, NT);

  // Layer 2: MFMA gemm -> fp8 rows; agg (BN2+ReLU -> bf16 h2, reuse hbuf)
  mfma_gemm_f8<<<768, 256, 0, stream>>>(hbuf, W2, dinv, f8buf, NT);
  agg128_f8_kernel<<<(N + 3) / 4, 256, 0, stream>>>((const uint2*)f8buf, dinv, row_start, pcnt,
                                                    edge_src, scv, bsv, hbuf, N);

  // Layer 3: bf16 out for pooling
  mfma_gemm_f8<<<768, 256, 0, stream>>>(hbuf, W3, dinv, f8buf, NT);
  agg128_f8_kernel<<<(N + 3) / 4, 256, 0, stream>>>((const uint2*)f8buf, dinv, row_start, pcnt,
                                                    edge_src, scv + 128, bsv + 128, hbuf, N);

  // Pool + head
  pool1_kernel<<<(N + 511) / 512, 256, 0, stream>>>((const uint*)hbuf, batch, gsums, N);
  head_kernel<<<G, 128, 0, stream>>>(gsums, batch, We, be, Wc1, bc1, Wc2, bc2, (float*)d_out, N);
}